// Round 13
// baseline (290.576 us; speedup 1.0000x reference)
//
#include <hip/hip_runtime.h>
#include <hip/hip_bf16.h>

typedef __hip_bfloat16 bf16;

__device__ __forceinline__ float b2f(bf16 x) { return __bfloat162float(x); }

// ---------------------------------------------------------------------------
// Problem constants  (resubmission of r11 source after two infra failures)
// ---------------------------------------------------------------------------
#define BB   2
#define FF   16
#define HH   64
#define WW   64
#define CC   16     // in/out channels == MID
#define NIMG (BB*FF)        // 32
#define PIX  (HH*WW)        // 4096
#define IMGSZ (PIX*CC)      // 65536 elements per image (channel-last)

// scale(=1/sqrt(2)) * log2(e): folded into staged Wq; softmax uses raw v_exp_f32
#define QSCALE_LOG2E 1.0201394f

// ---- 16-element bf16 I/O (intermediates A/R) ----
__device__ __forceinline__ void ld16bf(const bf16* p, float* x) {
    const uint4* p4 = reinterpret_cast<const uint4*>(p);
    uint4 u0 = p4[0], u1 = p4[1];
    unsigned uu[8] = {u0.x, u0.y, u0.z, u0.w, u1.x, u1.y, u1.z, u1.w};
    #pragma unroll
    for (int k = 0; k < 8; ++k) {
        union { unsigned u; float f; } lo, hi;
        lo.u = uu[k] << 16;
        hi.u = uu[k] & 0xffff0000u;
        x[2 * k] = lo.f;
        x[2 * k + 1] = hi.f;
    }
}

// ---- fp32 vector I/O ----
__device__ __forceinline__ void ld16f(const float* p, float* x) {
    const float4* p4 = reinterpret_cast<const float4*>(p);
    #pragma unroll
    for (int q = 0; q < 4; ++q) {
        float4 v = p4[q];
        x[4 * q] = v.x; x[4 * q + 1] = v.y; x[4 * q + 2] = v.z; x[4 * q + 3] = v.w;
    }
}

__device__ __forceinline__ unsigned packbf2(float a, float b) {
    union { bf16 h[2]; unsigned u; } pk;
    pk.h[0] = __float2bfloat16(a);
    pk.h[1] = __float2bfloat16(b);
    return pk.u;
}

// packed-f32 helpers (shaped for v_pk_fma_f32 / v_pk_mul_f32 fusion)
__device__ __forceinline__ float2 pk_fma2(float2 a, float b, float2 c) {
    return make_float2(fmaf(a.x, b, c.x), fmaf(a.y, b, c.y));
}
__device__ __forceinline__ float2 pk_mul2(float2 a, float b) {
    return make_float2(a.x * b, a.y * b);
}
__device__ __forceinline__ float2 pk_add2(float2 a, float2 b) {
    return make_float2(a.x + b.x, a.y + b.y);
}

// ---------------------------------------------------------------------------
// Kernel 1: conv stem on hidden (->A) and ref (->R, + fused emb-MLP).
// 2 threads per pixel, 8 out-channels each (2048 blocks -> 8 blocks/CU).
// ---------------------------------------------------------------------------
__global__ __launch_bounds__(256) void conv_in_kernel(
    const float* __restrict__ hid, const float* __restrict__ ref,
    const float* __restrict__ cw, const float* __restrict__ cb,
    const float* __restrict__ emb,
    const float* __restrict__ e1w, const float* __restrict__ e1b,
    const float* __restrict__ e2w, const float* __restrict__ e2b,
    bf16* __restrict__ A, bf16* __restrict__ R)
{
    __shared__ float wl[9 * 256];   // [tap][ic][oc]
    __shared__ float bl[16];
    __shared__ float hl[16];
    __shared__ float el[16];
    int t = threadIdx.x;
    {
        int ic = t >> 4, oc = t & 15;
        #pragma unroll
        for (int k = 0; k < 9; ++k)
            wl[k * 256 + t] = cw[(oc * 16 + ic) * 9 + k];
    }
    if (t < 16) bl[t] = cb[t];

    int gid2 = blockIdx.x * 128 + (t >> 1);   // pixel id, 0 .. 2*NIMG*PIX-1
    int ob   = (t & 1) * 8;                   // this thread's oc base
    int wi   = gid2 & 63;
    int hi   = (gid2 >> 6) & 63;
    int img2 = gid2 >> 12;                    // uniform per block (32 blk/img2)
    int isref = img2 >> 5;
    int img  = img2 & 31;
    int bi   = img >> 4;

    if (isref) {        // block-uniform branch: barriers inside are safe
        if (t < 16) {
            float acc = e1b[t];
            const float* er = emb + bi * 512;
            const float* wr = e1w + t * 512;
            for (int k = 0; k < 512; ++k) acc = fmaf(er[k], wr[k], acc);
            hl[t] = acc / (1.f + __expf(-acc));   // silu
        }
        __syncthreads();
        if (t < 16) {
            float acc = e2b[t];
            #pragma unroll
            for (int k = 0; k < 16; ++k) acc = fmaf(hl[k], e2w[t * 16 + k], acc);
            el[t] = acc;
        }
    }
    __syncthreads();

    const float* inp = (isref ? ref : hid) + (size_t)img * IMGSZ;
    float acc[8];
    #pragma unroll
    for (int oc = 0; oc < 8; ++oc)
        acc[oc] = bl[ob + oc] + (isref ? el[ob + oc] : 0.f);

    for (int ky = 0; ky < 3; ++ky) {
        int y = hi + ky - 1;
        if ((unsigned)y >= 64u) continue;
        for (int kx = 0; kx < 3; ++kx) {
            int x = wi + kx - 1;
            if ((unsigned)x >= 64u) continue;
            float xv[16];
            ld16f(inp + (((y << 6) + x) << 4), xv);
            const float* wt = &wl[(ky * 3 + kx) * 256 + ob];
            #pragma unroll
            for (int ic = 0; ic < 16; ++ic) {
                #pragma unroll
                for (int oc = 0; oc < 8; ++oc)
                    acc[oc] = fmaf(xv[ic], wt[ic * 16 + oc], acc[oc]);
            }
        }
    }
    bf16* op = (isref ? R : A) + ((size_t)(img * PIX + (hi << 6) + wi) << 4) + ob;
    union { unsigned u[4]; uint4 v; } pk;
    #pragma unroll
    for (int e = 0; e < 4; ++e)
        pk.u[e] = packbf2(acc[2 * e], acc[2 * e + 1]);
    *reinterpret_cast<uint4*>(op) = pk.v;
}

// ---------------------------------------------------------------------------
// Attention stage. NT = 2*SEQPB*S threads (2 threads per token in phase 1).
// Sequence s: tokens j<S/2 from A, j>=S/2 from R.
//   token j elem offset = (s/d2)*str1 + (s%d2)*str2 + j*tokStride
// Output (first S/2 tokens) written in place into A (bf16).
//
// K/V in LDS as bf16-packed uints (k01/v01 per head), separate arrays, token
// row stride 10 uints (conflict-free, VGPR-lean). Phase 2:
// thread = (seq, qgroup-of-8, head, key-quarter kq); key j = kq + 4*jj ->
// affine immediate addressing, banks 10kq+8jj+hd: only 2-way aliasing (free).
// Queries processed as float2 pairs (v_pk_fma-shaped). Merge via shfl_xor(1,2).
// Wq staged pre-scaled by scale*log2e; softmax = raw v_exp_f32 (exp2 domain).
// ---------------------------------------------------------------------------
template<int S, int SEQPB, int NT, int MINW>
__global__ __launch_bounds__(NT, MINW) void attn_kernel(
    bf16* __restrict__ A, const bf16* __restrict__ R,
    int d2, int str1, int str2, int tokStride,
    const float* __restrict__ wq, const float* __restrict__ wk,
    const float* __restrict__ wv, const float* __restrict__ wo,
    const float* __restrict__ bo, const float* __restrict__ gw,
    const float* __restrict__ bw)
{
    constexpr int HS  = S / 2;             // queries per sequence
    constexpr int KQ  = S / 4;             // keys per phase-2 thread (4-way)
    constexpr int ITEMS = NT / SEQPB;      // phase-2 threads per sequence
    constexpr int QB  = 8;                 // queries per phase-2 thread
    constexpr int KROW = 10;               // k/v token row stride (uints)
    constexpr int QROW = 20;               // q/o row stride (floats)
    constexpr int LSQ = (SEQPB == 1) ? 0 : ((SEQPB == 2) ? 1 : ((SEQPB == 4) ? 2 : 3));
    constexpr int NW3 = SEQPB * HS * 8 / NT;   // phase-3 reps (=2)
    static_assert(NT == 2 * SEQPB * S, "phase1 needs 2 threads/token");

    __shared__ float wql[256], wkl[256], wvl[256], wolT[256];
    __shared__ float bol[16], gl[16], blw[16];
    __shared__ __align__(16) unsigned kU[SEQPB * S * KROW];
    __shared__ __align__(16) unsigned vU[SEQPB * S * KROW];
    __shared__ __align__(16) float qoL[SEQPB * HS * QROW];
    __shared__ int bases[SEQPB];

    int t = threadIdx.x;
    if (t < 256) {
        wql[t] = wq[t] * QSCALE_LOG2E;            // fold softmax scale + log2e
        wkl[t] = wk[t];
        wvl[t] = wv[t];
        wolT[(t & 15) * 16 + (t >> 4)] = wo[t];   // transposed: [d][c]
    }
    if (t < 16) { bol[t] = bo[t]; gl[t] = gw[t]; blw[t] = bw[t]; }
    if (t < SEQPB) {
        int seq = blockIdx.x * SEQPB + t;
        bases[t] = (seq / d2) * str1 + (seq % d2) * str2;
    }
    __syncthreads();

    // ---- phase 1: token load, +posembed, LayerNorm, QKV -> LDS ----
    {
        int tokIdx = t >> 1, halfT = t & 1;
        int sq = tokIdx & (SEQPB - 1);     // sq fastest: adjacent lanes coalesce
        int i  = tokIdx >> LSQ;
        const bf16* src = (i < HS)
            ? (A + bases[sq] + (size_t)i * tokStride)
            : (R + bases[sq] + (size_t)(i - HS) * tokStride);
        float x[16];
        ld16bf(src, x);
        const float om[8] = {1.f, 0.31622776601683794f, 0.1f, 0.031622776601683794f,
                             0.01f, 0.0031622776601683794f, 0.001f, 0.00031622776601683794f};
        float fi = (float)i;
        #pragma unroll
        for (int k = 0; k < 8; ++k) {
            float sv, cv;
            __sincosf(fi * om[k], &sv, &cv);
            x[k]     += sv;
            x[k + 8] += cv;
        }
        float m = 0.f;
        #pragma unroll
        for (int c = 0; c < 16; ++c) m += x[c];
        m *= (1.f / 16.f);
        float var = 0.f;
        #pragma unroll
        for (int c = 0; c < 16; ++c) { float d = x[c] - m; var = fmaf(d, d, var); }
        var *= (1.f / 16.f);
        float rs = rsqrtf(var + 1e-5f);
        float xn[16];
        #pragma unroll
        for (int c = 0; c < 16; ++c) xn[c] = (x[c] - m) * rs * gl[c] + blw[c];

        int db = halfT * 8;                 // this thread's 8 output dims
        float qv[8], kv[8], vv[8];
        #pragma unroll
        for (int dd = 0; dd < 8; ++dd) {
            int d = db + dd;
            float aq = 0.f, ak = 0.f, av = 0.f;
            #pragma unroll
            for (int c = 0; c < 16; ++c) {
                aq = fmaf(xn[c], wql[d * 16 + c], aq);
                ak = fmaf(xn[c], wkl[d * 16 + c], ak);
                av = fmaf(xn[c], wvl[d * 16 + c], av);
            }
            qv[dd] = aq; kv[dd] = ak; vv[dd] = av;
        }
        int row = (sq * S + i) * KROW + 4 * halfT;   // uint index, even
        uint2* kr = reinterpret_cast<uint2*>(&kU[row]);
        uint2* vr = reinterpret_cast<uint2*>(&vU[row]);
        kr[0] = make_uint2(packbf2(kv[0], kv[1]), packbf2(kv[2], kv[3]));
        kr[1] = make_uint2(packbf2(kv[4], kv[5]), packbf2(kv[6], kv[7]));
        vr[0] = make_uint2(packbf2(vv[0], vv[1]), packbf2(vv[2], vv[3]));
        vr[1] = make_uint2(packbf2(vv[4], vv[5]), packbf2(vv[6], vv[7]));
        if (i < HS) {
            float* qrow = &qoL[(sq * HS + i) * QROW + db];
            reinterpret_cast<float4*>(qrow)[0] = make_float4(qv[0], qv[1], qv[2], qv[3]);
            reinterpret_cast<float4*>(qrow)[1] = make_float4(qv[4], qv[5], qv[6], qv[7]);
        }
    }
    __syncthreads();

    // ---- phase 2: single-pass softmax (exp2 domain), 4-way key split,
    //      queries in float2 pairs (packed-f32-shaped) ----
    int sq2 = t / ITEMS;
    int r   = t % ITEMS;
    int kq  = r & 3;           // key quarter
    int hd  = (r >> 2) & 7;    // head
    int qg  = r >> 5;          // query group of QB=8
    {
        float2 q02[4], q12[4], l2[4], a02[4], a12[4];
        #pragma unroll
        for (int pp = 0; pp < 4; ++pp) {
            float2 qa = *reinterpret_cast<const float2*>(
                &qoL[(sq2 * HS + qg * QB + 2 * pp) * QROW + 2 * hd]);
            float2 qb = *reinterpret_cast<const float2*>(
                &qoL[(sq2 * HS + qg * QB + 2 * pp + 1) * QROW + 2 * hd]);
            q02[pp] = make_float2(qa.x, qb.x);
            q12[pp] = make_float2(qa.y, qb.y);
            l2[pp] = make_float2(0.f, 0.f);
            a02[pp] = make_float2(0.f, 0.f);
            a12[pp] = make_float2(0.f, 0.f);
        }
        const unsigned* kp = &kU[(sq2 * S + kq) * KROW + hd];
        const unsigned* vp = &vU[(sq2 * S + kq) * KROW + hd];
        #pragma unroll 8
        for (int jj = 0; jj < KQ; ++jj) {            // key j = kq + 4*jj
            unsigned ku = kp[jj * 4 * KROW];
            unsigned vu = vp[jj * 4 * KROW];
            union { unsigned u; float f; } k0, k1, v0, v1;
            k0.u = ku << 16; k1.u = ku & 0xffff0000u;
            v0.u = vu << 16; v1.u = vu & 0xffff0000u;
            #pragma unroll
            for (int pp = 0; pp < 4; ++pp) {
                float2 s = pk_fma2(q02[pp], k0.f, pk_mul2(q12[pp], k1.f));
                float2 p = make_float2(__builtin_amdgcn_exp2f(s.x),
                                       __builtin_amdgcn_exp2f(s.y));
                l2[pp]  = pk_add2(l2[pp], p);
                a02[pp] = pk_fma2(p, v0.f, a02[pp]);
                a12[pp] = pk_fma2(p, v1.f, a12[pp]);
            }
        }
        #pragma unroll
        for (int pp = 0; pp < 4; ++pp) {
            l2[pp].x  += __shfl_xor(l2[pp].x, 1);  l2[pp].y  += __shfl_xor(l2[pp].y, 1);
            a02[pp].x += __shfl_xor(a02[pp].x, 1); a02[pp].y += __shfl_xor(a02[pp].y, 1);
            a12[pp].x += __shfl_xor(a12[pp].x, 1); a12[pp].y += __shfl_xor(a12[pp].y, 1);
            l2[pp].x  += __shfl_xor(l2[pp].x, 2);  l2[pp].y  += __shfl_xor(l2[pp].y, 2);
            a02[pp].x += __shfl_xor(a02[pp].x, 2); a02[pp].y += __shfl_xor(a02[pp].y, 2);
            a12[pp].x += __shfl_xor(a12[pp].x, 2); a12[pp].y += __shfl_xor(a12[pp].y, 2);
        }
        __syncthreads();   // all q reads done; safe to overwrite qoL with o
        if (kq == 0) {
            #pragma unroll
            for (int pp = 0; pp < 4; ++pp) {
                float inva = 1.f / l2[pp].x;
                float invb = 1.f / l2[pp].y;
                *reinterpret_cast<float2*>(
                    &qoL[(sq2 * HS + qg * QB + 2 * pp) * QROW + 2 * hd]) =
                    make_float2(a02[pp].x * inva, a12[pp].x * inva);
                *reinterpret_cast<float2*>(
                    &qoL[(sq2 * HS + qg * QB + 2 * pp + 1) * QROW + 2 * hd]) =
                    make_float2(a02[pp].y * invb, a12[pp].y * invb);
            }
        }
    }
    __syncthreads();

    // ---- phase 3: out-proj, in-place bf16x2 write; sq fastest for lines ----
    #pragma unroll
    for (int rep = 0; rep < NW3; ++rep) {
        int idx = t + rep * NT;           // < SEQPB*HS*8
        int cp  = idx & 7;                // channel pair
        int g   = idx >> 3;
        int sq3 = g & (SEQPB - 1);
        int tok = g >> LSQ;
        const float* orow = &qoL[(sq3 * HS + tok) * QROW];
        float acc0 = bol[2 * cp], acc1 = bol[2 * cp + 1];
        #pragma unroll
        for (int d = 0; d < 16; ++d) {
            acc0 = fmaf(orow[d], wolT[d * 16 + 2 * cp], acc0);
            acc1 = fmaf(orow[d], wolT[d * 16 + 2 * cp + 1], acc1);
        }
        *reinterpret_cast<unsigned*>(
            A + bases[sq3] + (size_t)tok * tokStride + 2 * cp) =
            packbf2(acc0, acc1);
    }
}

// ---------------------------------------------------------------------------
// Kernel 5: out = hidden + conv(rest). 2 threads/pixel, 8 oc each.
// ---------------------------------------------------------------------------
__global__ __launch_bounds__(256) void conv_out_kernel(
    const bf16* __restrict__ A, const float* __restrict__ hid,
    const float* __restrict__ pw, const float* __restrict__ pb,
    float* __restrict__ out)
{
    __shared__ float wl[9 * 256];
    __shared__ float bl[16];
    int t = threadIdx.x;
    {
        int ic = t >> 4, oc = t & 15;
        #pragma unroll
        for (int k = 0; k < 9; ++k)
            wl[k * 256 + t] = pw[(oc * 16 + ic) * 9 + k];
    }
    if (t < 16) bl[t] = pb[t];
    __syncthreads();

    int gid2 = blockIdx.x * 128 + (t >> 1);   // pixel id, 0 .. NIMG*PIX-1
    int ob   = (t & 1) * 8;
    int wi = gid2 & 63, hi = (gid2 >> 6) & 63;
    int img = gid2 >> 12;
    const bf16* inp = A + ((size_t)img << 16);
    float acc[8];
    #pragma unroll
    for (int oc = 0; oc < 8; ++oc) acc[oc] = bl[ob + oc];

    for (int ky = 0; ky < 3; ++ky) {
        int y = hi + ky - 1;
        if ((unsigned)y >= 64u) continue;
        for (int kx = 0; kx < 3; ++kx) {
            int x = wi + kx - 1;
            if ((unsigned)x >= 64u) continue;
            float xv[16];
            ld16bf(inp + (((y << 6) + x) << 4), xv);
            const float* wt = &wl[(ky * 3 + kx) * 256 + ob];
            #pragma unroll
            for (int ic = 0; ic < 16; ++ic) {
                #pragma unroll
                for (int oc = 0; oc < 8; ++oc)
                    acc[oc] = fmaf(xv[ic], wt[ic * 16 + oc], acc[oc]);
            }
        }
    }
    size_t off = (((size_t)gid2) << 4) + ob;
    const float4* h4 = reinterpret_cast<const float4*>(hid + off);
    float4 ha = h4[0], hb = h4[1];
    float4 r0 = make_float4(acc[0] + ha.x, acc[1] + ha.y, acc[2] + ha.z, acc[3] + ha.w);
    float4 r1 = make_float4(acc[4] + hb.x, acc[5] + hb.y, acc[6] + hb.z, acc[7] + hb.w);
    float4* o4 = reinterpret_cast<float4*>(out + off);
    o4[0] = r0;
    o4[1] = r1;
}

// ---------------------------------------------------------------------------
extern "C" void kernel_launch(void* const* d_in, const int* in_sizes, int n_in,
                              void* d_out, int out_size, void* d_ws, size_t ws_size,
                              hipStream_t stream) {
    const float* hid  = (const float*)d_in[0];
    const float* ref  = (const float*)d_in[1];
    const float* emb  = (const float*)d_in[2];
    const float* ciw  = (const float*)d_in[3];
    const float* cib  = (const float*)d_in[4];
    const float* e1w  = (const float*)d_in[5];
    const float* e1b  = (const float*)d_in[6];
    const float* e2w  = (const float*)d_in[7];
    const float* e2b  = (const float*)d_in[8];
    const float* wqx  = (const float*)d_in[9];
    const float* wkx  = (const float*)d_in[10];
    const float* wvx  = (const float*)d_in[11];
    const float* wox  = (const float*)d_in[12];
    const float* box_ = (const float*)d_in[13];
    const float* wqy  = (const float*)d_in[14];
    const float* wky  = (const float*)d_in[15];
    const float* wvy  = (const float*)d_in[16];
    const float* woy  = (const float*)d_in[17];
    const float* boy  = (const float*)d_in[18];
    const float* wqt  = (const float*)d_in[19];
    const float* wkt  = (const float*)d_in[20];
    const float* wvt  = (const float*)d_in[21];
    const float* wot  = (const float*)d_in[22];
    const float* bot  = (const float*)d_in[23];
    const float* ng   = (const float*)d_in[24];
    const float* nb   = (const float*)d_in[25];
    const float* pjw  = (const float*)d_in[26];
    const float* pjb  = (const float*)d_in[27];

    bf16* A = (bf16*)d_ws;     // 4 MiB in workspace
    bf16* R = (bf16*)d_out;    // 4 MiB scratch inside the 8 MiB f32 output buf
                               // (fully overwritten by conv_out at the end)

    conv_in_kernel<<<(2 * NIMG * PIX * 2) / 256, 256, 0, stream>>>(
        hid, ref, ciw, cib, emb, e1w, e1b, e2w, e2b, A, R);

    // Stage X: seq=(b,f,h), S=2W=128, token stride 16 (contiguous rows)
    attn_kernel<128, 1, 256, 6><<<BB * FF * HH, 256, 0, stream>>>(
        A, R, 1, WW * CC, 0, CC, wqx, wkx, wvx, wox, box_, ng, nb);
    // Stage Y: seq=(b,f,w), S=2H=128, tok stride W*C; 2 consecutive w, NT=512
    attn_kernel<128, 2, 512, 6><<<(BB * FF * WW) / 2, 512, 0, stream>>>(
        A, R, WW, IMGSZ, CC, WW * CC, wqy, wky, wvy, woy, boy, ng, nb);
    // Stage T: seq=(b,h,w), S=2F=32, tok str H*W*C; 4 consecutive w, NT=256
    attn_kernel<32, 4, 256, 6><<<(BB * HH * WW) / 4, 256, 0, stream>>>(
        A, R, HH * WW, FF * IMGSZ, CC, IMGSZ, wqt, wkt, wvt, wot, bot, ng, nb);

    conv_out_kernel<<<(NIMG * PIX * 2) / 256, 256, 0, stream>>>(A, hid, pjw, pjb, (float*)d_out);
}

// Round 14
// 272.519 us; speedup vs baseline: 1.0663x; 1.0663x over previous
//
#include <hip/hip_runtime.h>
#include <hip/hip_bf16.h>

typedef __hip_bfloat16 bf16;

__device__ __forceinline__ float b2f(bf16 x) { return __bfloat162float(x); }

// ---------------------------------------------------------------------------
// Problem constants   (reversion to the r8 optimum: 276.2 us measured)
// ---------------------------------------------------------------------------
#define BB   2
#define FF   16
#define HH   64
#define WW   64
#define CC   16     // in/out channels == MID
#define NIMG (BB*FF)        // 32
#define PIX  (HH*WW)        // 4096
#define IMGSZ (PIX*CC)      // 65536 elements per image (channel-last)

// scale(=1/sqrt(2)) * log2(e): folded into staged Wq; softmax uses raw v_exp_f32
#define QSCALE_LOG2E 1.0201394f

// ---- 16-element bf16 I/O (intermediates A/R) ----
__device__ __forceinline__ void ld16bf(const bf16* p, float* x) {
    const uint4* p4 = reinterpret_cast<const uint4*>(p);
    uint4 u0 = p4[0], u1 = p4[1];
    unsigned uu[8] = {u0.x, u0.y, u0.z, u0.w, u1.x, u1.y, u1.z, u1.w};
    #pragma unroll
    for (int k = 0; k < 8; ++k) {
        union { unsigned u; float f; } lo, hi;
        lo.u = uu[k] << 16;
        hi.u = uu[k] & 0xffff0000u;
        x[2 * k] = lo.f;
        x[2 * k + 1] = hi.f;
    }
}
__device__ __forceinline__ void st16bf(bf16* p, const float* x) {
    union { bf16 h[16]; uint4 u[2]; } o;
    #pragma unroll
    for (int k = 0; k < 16; ++k) o.h[k] = __float2bfloat16(x[k]);
    uint4* p4 = reinterpret_cast<uint4*>(p);
    p4[0] = o.u[0];
    p4[1] = o.u[1];
}

// ---- 16-element fp32 I/O (global inputs/outputs) ----
__device__ __forceinline__ void ld16f(const float* p, float* x) {
    const float4* p4 = reinterpret_cast<const float4*>(p);
    #pragma unroll
    for (int q = 0; q < 4; ++q) {
        float4 v = p4[q];
        x[4 * q] = v.x; x[4 * q + 1] = v.y; x[4 * q + 2] = v.z; x[4 * q + 3] = v.w;
    }
}
__device__ __forceinline__ void st16f(float* p, const float* x) {
    float4* p4 = reinterpret_cast<float4*>(p);
    #pragma unroll
    for (int q = 0; q < 4; ++q)
        p4[q] = make_float4(x[4 * q], x[4 * q + 1], x[4 * q + 2], x[4 * q + 3]);
}

__device__ __forceinline__ unsigned packbf2(float a, float b) {
    union { bf16 h[2]; unsigned u; } pk;
    pk.h[0] = __float2bfloat16(a);
    pk.h[1] = __float2bfloat16(b);
    return pk.u;
}

// ---------------------------------------------------------------------------
// Kernel 1: conv stem on hidden (->A) and ref (->R, + fused emb-MLP).
// ---------------------------------------------------------------------------
__global__ __launch_bounds__(256) void conv_in_kernel(
    const float* __restrict__ hid, const float* __restrict__ ref,
    const float* __restrict__ cw, const float* __restrict__ cb,
    const float* __restrict__ emb,
    const float* __restrict__ e1w, const float* __restrict__ e1b,
    const float* __restrict__ e2w, const float* __restrict__ e2b,
    bf16* __restrict__ A, bf16* __restrict__ R)
{
    __shared__ float wl[9 * 256];   // [tap][ic][oc]
    __shared__ float bl[16];
    __shared__ float hl[16];
    __shared__ float el[16];
    int t = threadIdx.x;
    {
        int ic = t >> 4, oc = t & 15;
        #pragma unroll
        for (int k = 0; k < 9; ++k)
            wl[k * 256 + t] = cw[(oc * 16 + ic) * 9 + k];
    }
    if (t < 16) bl[t] = cb[t];

    int gid  = blockIdx.x * 256 + t;       // 0 .. 2*NIMG*PIX-1
    int wi   = gid & 63;
    int hi   = (gid >> 6) & 63;
    int img2 = gid >> 12;                  // uniform per block (16 blocks/img)
    int isref = img2 >> 5;
    int img  = img2 & 31;
    int bi   = img >> 4;

    if (isref) {        // block-uniform branch: barriers inside are safe
        if (t < 16) {
            float acc = e1b[t];
            const float* er = emb + bi * 512;
            const float* wr = e1w + t * 512;
            for (int k = 0; k < 512; ++k) acc = fmaf(er[k], wr[k], acc);
            hl[t] = acc / (1.f + __expf(-acc));   // silu
        }
        __syncthreads();
        if (t < 16) {
            float acc = e2b[t];
            #pragma unroll
            for (int k = 0; k < 16; ++k) acc = fmaf(hl[k], e2w[t * 16 + k], acc);
            el[t] = acc;
        }
    }
    __syncthreads();

    const float* inp = (isref ? ref : hid) + (size_t)img * IMGSZ;
    float acc[16];
    #pragma unroll
    for (int oc = 0; oc < 16; ++oc)
        acc[oc] = bl[oc] + (isref ? el[oc] : 0.f);

    for (int ky = 0; ky < 3; ++ky) {
        int y = hi + ky - 1;
        if ((unsigned)y >= 64u) continue;
        for (int kx = 0; kx < 3; ++kx) {
            int x = wi + kx - 1;
            if ((unsigned)x >= 64u) continue;
            float xv[16];
            ld16f(inp + (((y << 6) + x) << 4), xv);
            const float* wt = &wl[(ky * 3 + kx) * 256];
            #pragma unroll
            for (int ic = 0; ic < 16; ++ic) {
                #pragma unroll
                for (int oc = 0; oc < 16; ++oc)
                    acc[oc] = fmaf(xv[ic], wt[ic * 16 + oc], acc[oc]);
            }
        }
    }
    bf16* op = (isref ? R : A) + ((size_t)(img * PIX + (hi << 6) + wi) << 4);
    st16bf(op, acc);
}

// ---------------------------------------------------------------------------
// Attention stage. 256 threads; TPT = 256/(SEQPB*S) threads per token (1 or 2).
// Sequence s: tokens j<S/2 from A, j>=S/2 from R.
//   token j elem offset = (s/d2)*str1 + (s%d2)*str2 + j*tokStride
// Output (first S/2 tokens) written in place into A (bf16).
//
// K/V in LDS as bf16-packed uints (k01/v01 per head), separate arrays, token
// row stride 10 uints -> phase-2 lane banks {hd} u {10+hd}: conflict-free,
// affine jj addressing. Lane maps put sq fastest so blocks with consecutive
// sequences (Y: 2, T: 4) make 64/128B-contiguous global accesses.
// Wq staged pre-scaled by scale*log2e; softmax = raw v_exp_f32 (exp2 domain).
// ---------------------------------------------------------------------------
template<int S, int SEQPB, int MINW>
__global__ __launch_bounds__(256, MINW) void attn_kernel(
    bf16* __restrict__ A, const bf16* __restrict__ R,
    int d2, int str1, int str2, int tokStride,
    const float* __restrict__ wq, const float* __restrict__ wk,
    const float* __restrict__ wv, const float* __restrict__ wo,
    const float* __restrict__ bo, const float* __restrict__ gw,
    const float* __restrict__ bw)
{
    constexpr int HS  = S / 2;             // queries per sequence
    constexpr int KQ  = S / 2;             // keys per phase-2 thread (parity)
    constexpr int TPT = 256 / (SEQPB * S); // threads per token: 1 or 2
    constexpr int ITEMS = 256 / SEQPB;     // phase-2 threads per sequence
    constexpr int NQG = ITEMS / 16;        // query groups per sequence
    constexpr int QB  = HS / NQG;          // queries per phase-2 thread
    constexpr int KROW = 10;               // k/v token row stride (uints)
    constexpr int QROW = 20;               // q/o row stride (floats)
    constexpr int LSQ = (SEQPB == 1) ? 0 : ((SEQPB == 2) ? 1 : 2);
    constexpr int NW3 = SEQPB * HS * 8 / 256;  // phase-3 reps

    __shared__ float wql[256], wkl[256], wvl[256], wolT[256];
    __shared__ float bol[16], gl[16], blw[16];
    __shared__ __align__(16) unsigned kU[SEQPB * S * KROW];
    __shared__ __align__(16) unsigned vU[SEQPB * S * KROW];
    __shared__ __align__(16) float qoL[SEQPB * HS * QROW];
    __shared__ int bases[SEQPB];

    int t = threadIdx.x;
    wql[t] = wq[t] * QSCALE_LOG2E;            // fold softmax scale + log2e
    wkl[t] = wk[t];
    wvl[t] = wv[t];
    wolT[(t & 15) * 16 + (t >> 4)] = wo[t];   // transposed: [d][c]
    if (t < 16) { bol[t] = bo[t]; gl[t] = gw[t]; blw[t] = bw[t]; }
    if (t < SEQPB) {
        int seq = blockIdx.x * SEQPB + t;
        bases[t] = (seq / d2) * str1 + (seq % d2) * str2;
    }
    __syncthreads();

    // ---- phase 1: token load, +posembed, LayerNorm, QKV -> LDS ----
    {
        int tokIdx, sq, i, db, ndim;
        if (TPT == 2) {
            tokIdx = t >> 1;
            db = (t & 1) * 8;   // this thread's 8 output dims
            ndim = 8;
        } else {
            tokIdx = t;
            db = 0;             // all 16 dims
            ndim = 16;
        }
        sq = tokIdx & (SEQPB - 1);     // sq fastest: adjacent lanes coalesce
        i  = tokIdx >> LSQ;
        const bf16* src = (i < HS)
            ? (A + bases[sq] + (size_t)i * tokStride)
            : (R + bases[sq] + (size_t)(i - HS) * tokStride);
        float x[16];
        ld16bf(src, x);
        const float om[8] = {1.f, 0.31622776601683794f, 0.1f, 0.031622776601683794f,
                             0.01f, 0.0031622776601683794f, 0.001f, 0.00031622776601683794f};
        float fi = (float)i;
        #pragma unroll
        for (int k = 0; k < 8; ++k) {
            float sv, cv;
            __sincosf(fi * om[k], &sv, &cv);
            x[k]     += sv;
            x[k + 8] += cv;
        }
        float m = 0.f;
        #pragma unroll
        for (int c = 0; c < 16; ++c) m += x[c];
        m *= (1.f / 16.f);
        float var = 0.f;
        #pragma unroll
        for (int c = 0; c < 16; ++c) { float d = x[c] - m; var = fmaf(d, d, var); }
        var *= (1.f / 16.f);
        float rs = rsqrtf(var + 1e-5f);
        float xn[16];
        #pragma unroll
        for (int c = 0; c < 16; ++c) xn[c] = (x[c] - m) * rs * gl[c] + blw[c];

        float qv[16], kv[16], vv[16];
        #pragma unroll
        for (int dd = 0; dd < 16; ++dd) {
            if (dd >= ndim) break;      // ndim is constexpr-foldable per TPT
            int d = db + dd;
            float aq = 0.f, ak = 0.f, av = 0.f;
            #pragma unroll
            for (int c = 0; c < 16; ++c) {
                aq = fmaf(xn[c], wql[d * 16 + c], aq);
                ak = fmaf(xn[c], wkl[d * 16 + c], ak);
                av = fmaf(xn[c], wvl[d * 16 + c], av);
            }
            qv[dd] = aq; kv[dd] = ak; vv[dd] = av;
        }
        int row = (sq * S + i) * KROW + (db >> 1);   // uint index, even
        uint2* kr = reinterpret_cast<uint2*>(&kU[row]);
        uint2* vr = reinterpret_cast<uint2*>(&vU[row]);
        #pragma unroll
        for (int e = 0; e < ndim / 4; ++e) {
            kr[e] = make_uint2(packbf2(kv[4 * e], kv[4 * e + 1]),
                               packbf2(kv[4 * e + 2], kv[4 * e + 3]));
            vr[e] = make_uint2(packbf2(vv[4 * e], vv[4 * e + 1]),
                               packbf2(vv[4 * e + 2], vv[4 * e + 3]));
        }
        if (i < HS) {
            float* qrow = &qoL[(sq * HS + i) * QROW + db];
            #pragma unroll
            for (int e = 0; e < ndim / 4; ++e)
                reinterpret_cast<float4*>(qrow)[e] =
                    make_float4(qv[4 * e], qv[4 * e + 1], qv[4 * e + 2], qv[4 * e + 3]);
        }
    }
    __syncthreads();

    // ---- phase 2: single-pass softmax (exp2 domain), parity key split ----
    int sq2 = t / ITEMS;
    int r   = t % ITEMS;
    int qg  = r >> 4;          // query group (QB queries)
    int hd  = (r >> 1) & 7;    // head
    int half = r & 1;          // key parity
    {
        float q0[QB], q1[QB], l[QB], a0[QB], a1[QB];
        #pragma unroll
        for (int qq = 0; qq < QB; ++qq) {
            float2 qv = *reinterpret_cast<const float2*>(
                &qoL[(sq2 * HS + qg * QB + qq) * QROW + 2 * hd]);
            q0[qq] = qv.x;                 // already scaled (Wq fold)
            q1[qq] = qv.y;
            l[qq] = 0.f; a0[qq] = 0.f; a1[qq] = 0.f;
        }
        const unsigned* kp = &kU[(sq2 * S + half) * KROW + hd];
        const unsigned* vp = &vU[(sq2 * S + half) * KROW + hd];
        #pragma unroll 8
        for (int jj = 0; jj < KQ; ++jj) {            // key j = 2*jj + half
            unsigned ku = kp[jj * 2 * KROW];
            unsigned vu = vp[jj * 2 * KROW];
            union { unsigned u; float f; } k0, k1, v0, v1;
            k0.u = ku << 16; k1.u = ku & 0xffff0000u;
            v0.u = vu << 16; v1.u = vu & 0xffff0000u;
            #pragma unroll
            for (int qq = 0; qq < QB; ++qq) {
                float s = fmaf(q0[qq], k0.f, q1[qq] * k1.f);
                float p = __builtin_amdgcn_exp2f(s);
                l[qq] += p;
                a0[qq] = fmaf(p, v0.f, a0[qq]);
                a1[qq] = fmaf(p, v1.f, a1[qq]);
            }
        }
        #pragma unroll
        for (int qq = 0; qq < QB; ++qq) {
            l[qq]  += __shfl_xor(l[qq], 1);
            a0[qq] += __shfl_xor(a0[qq], 1);
            a1[qq] += __shfl_xor(a1[qq], 1);
        }
        __syncthreads();   // all q reads done; safe to overwrite qoL with o
        if (half == 0) {
            #pragma unroll
            for (int qq = 0; qq < QB; ++qq) {
                float inv = 1.f / l[qq];
                *reinterpret_cast<float2*>(
                    &qoL[(sq2 * HS + qg * QB + qq) * QROW + 2 * hd]) =
                    make_float2(a0[qq] * inv, a1[qq] * inv);
            }
        }
    }
    __syncthreads();

    // ---- phase 3: out-proj, in-place bf16x2 write; sq fastest for lines ----
    #pragma unroll
    for (int rep = 0; rep < NW3; ++rep) {
        int idx = t + rep * 256;          // < SEQPB*HS*8
        int cp  = idx & 7;                // channel pair
        int g   = idx >> 3;
        int sq3 = g & (SEQPB - 1);
        int tok = g >> LSQ;
        const float* orow = &qoL[(sq3 * HS + tok) * QROW];
        float acc0 = bol[2 * cp], acc1 = bol[2 * cp + 1];
        #pragma unroll
        for (int d = 0; d < 16; ++d) {
            acc0 = fmaf(orow[d], wolT[d * 16 + 2 * cp], acc0);
            acc1 = fmaf(orow[d], wolT[d * 16 + 2 * cp + 1], acc1);
        }
        *reinterpret_cast<unsigned*>(
            A + bases[sq3] + (size_t)tok * tokStride + 2 * cp) =
            packbf2(acc0, acc1);
    }
}

// ---------------------------------------------------------------------------
// Kernel 5: out = hidden + conv(rest)
// ---------------------------------------------------------------------------
__global__ __launch_bounds__(256) void conv_out_kernel(
    const bf16* __restrict__ A, const float* __restrict__ hid,
    const float* __restrict__ pw, const float* __restrict__ pb,
    float* __restrict__ out)
{
    __shared__ float wl[9 * 256];
    __shared__ float bl[16];
    int t = threadIdx.x;
    {
        int ic = t >> 4, oc = t & 15;
        #pragma unroll
        for (int k = 0; k < 9; ++k)
            wl[k * 256 + t] = pw[(oc * 16 + ic) * 9 + k];
    }
    if (t < 16) bl[t] = pb[t];
    __syncthreads();

    int gid = blockIdx.x * 256 + t;   // 0 .. NIMG*PIX-1
    int wi = gid & 63, hi = (gid >> 6) & 63;
    int img = gid >> 12;
    const bf16* inp = A + ((size_t)img << 16);
    float acc[16];
    #pragma unroll
    for (int oc = 0; oc < 16; ++oc) acc[oc] = bl[oc];

    for (int ky = 0; ky < 3; ++ky) {
        int y = hi + ky - 1;
        if ((unsigned)y >= 64u) continue;
        for (int kx = 0; kx < 3; ++kx) {
            int x = wi + kx - 1;
            if ((unsigned)x >= 64u) continue;
            float xv[16];
            ld16bf(inp + (((y << 6) + x) << 4), xv);
            const float* wt = &wl[(ky * 3 + kx) * 256];
            #pragma unroll
            for (int ic = 0; ic < 16; ++ic) {
                #pragma unroll
                for (int oc = 0; oc < 16; ++oc)
                    acc[oc] = fmaf(xv[ic], wt[ic * 16 + oc], acc[oc]);
            }
        }
    }
    size_t off = ((size_t)gid) << 4;
    float hv[16];
    ld16f(hid + off, hv);
    float res[16];
    #pragma unroll
    for (int k = 0; k < 16; ++k) res[k] = acc[k] + hv[k];
    st16f(out + off, res);
}

// ---------------------------------------------------------------------------
extern "C" void kernel_launch(void* const* d_in, const int* in_sizes, int n_in,
                              void* d_out, int out_size, void* d_ws, size_t ws_size,
                              hipStream_t stream) {
    const float* hid  = (const float*)d_in[0];
    const float* ref  = (const float*)d_in[1];
    const float* emb  = (const float*)d_in[2];
    const float* ciw  = (const float*)d_in[3];
    const float* cib  = (const float*)d_in[4];
    const float* e1w  = (const float*)d_in[5];
    const float* e1b  = (const float*)d_in[6];
    const float* e2w  = (const float*)d_in[7];
    const float* e2b  = (const float*)d_in[8];
    const float* wqx  = (const float*)d_in[9];
    const float* wkx  = (const float*)d_in[10];
    const float* wvx  = (const float*)d_in[11];
    const float* wox  = (const float*)d_in[12];
    const float* box_ = (const float*)d_in[13];
    const float* wqy  = (const float*)d_in[14];
    const float* wky  = (const float*)d_in[15];
    const float* wvy  = (const float*)d_in[16];
    const float* woy  = (const float*)d_in[17];
    const float* boy  = (const float*)d_in[18];
    const float* wqt  = (const float*)d_in[19];
    const float* wkt  = (const float*)d_in[20];
    const float* wvt  = (const float*)d_in[21];
    const float* wot  = (const float*)d_in[22];
    const float* bot  = (const float*)d_in[23];
    const float* ng   = (const float*)d_in[24];
    const float* nb   = (const float*)d_in[25];
    const float* pjw  = (const float*)d_in[26];
    const float* pjb  = (const float*)d_in[27];

    bf16* A = (bf16*)d_ws;     // 4 MiB in workspace
    bf16* R = (bf16*)d_out;    // 4 MiB scratch inside the 8 MiB f32 output buf
                               // (fully overwritten by conv_out at the end)

    conv_in_kernel<<<(2 * NIMG * PIX) / 256, 256, 0, stream>>>(
        hid, ref, ciw, cib, emb, e1w, e1b, e2w, e2b, A, R);

    // Stage X: seq=(b,f,h), S=2W=128, token stride 16 (contiguous rows), TPT=2
    attn_kernel<128, 1, 8><<<BB * FF * HH, 256, 0, stream>>>(
        A, R, 1, WW * CC, 0, CC, wqx, wkx, wvx, wox, box_, ng, nb);
    // Stage Y: seq=(b,f,w), S=2H=128, tok stride W*C; 2 consecutive w, TPT=1
    attn_kernel<128, 2, 4><<<(BB * FF * WW) / 2, 256, 0, stream>>>(
        A, R, WW, IMGSZ, CC, WW * CC, wqy, wky, wvy, woy, boy, ng, nb);
    // Stage T: seq=(b,h,w), S=2F=32, tok stride H*W*C; 4 consecutive w, TPT=2
    attn_kernel<32, 4, 8><<<(BB * HH * WW) / 4, 256, 0, stream>>>(
        A, R, HH * WW, FF * IMGSZ, CC, IMGSZ, wqt, wkt, wvt, wot, bot, ng, nb);

    conv_out_kernel<<<(NIMG * PIX) / 256, 256, 0, stream>>>(A, hid, pjw, pjb, (float*)d_out);
}